// Round 5
// baseline (5024.977 us; speedup 1.0000x reference)
//
#include <hip/hip_runtime.h>
#include <hip/hip_bf16.h>

// Persistent bidirectional LSTM for MI355X. B=32, T=512, H=512.
// 128 persistent WGs (2 dirs x 64), fp16 weight fragments stationary in VGPRs.
//
// R4 post-mortem: 7.4 us/step; chain still had 4 dependent L3 round trips
// (h-store drain, counter-add visibility, poll detect, h fetch) + x loads on
// the critical path + 2 barriers. R5 collapses publish->consume to ONE store
// + ONE load: h is published as stamped u64 (hi32 = step, lo32 = 2xfp16) into
// a per-step ring; readers poll the data words directly (bypass loads) until
// the stamp matches. x is pre-converted to fp16 in ws and prefetched into
// registers one step ahead (off-chain). Fallback to R4 scheme if ws is small.

#define HDIM 512
#define TDIM 512
#define BDIM 32
#define NWG  64     // workgroups per direction
#define NTHR 256
#define CSTRIDE 16  // ints per counter slot (fallback path)
#define SLOTS (TDIM + 1)

typedef float f32x4 __attribute__((ext_vector_type(4)));
typedef _Float16 half8 __attribute__((ext_vector_type(8)));
typedef _Float16 half4 __attribute__((ext_vector_type(4)));
typedef unsigned int u32x4 __attribute__((ext_vector_type(4)));
typedef unsigned long long u64x2 __attribute__((ext_vector_type(2)));
typedef unsigned long long u64;

#define SLICE_INTS (BDIM * HDIM / 2)   // fallback: 8192 ints = 32 KB slice
#define SLICE_U64  (BDIM * HDIM / 2)   // primary: 8192 u64 = 64 KB slice

__device__ __forceinline__ float sigm(float x) { return 1.f / (1.f + __expf(-x)); }
__device__ __forceinline__ float tanh_f(float x) { return 1.f - 2.f / (__expf(2.f * x) + 1.f); }

// ================= primary (stamped-ring) path =================
// ws: [0,65664) counters (unused, layout compat). [65664, +33554432) xhalf
// fp16 [B][T][H]. Then ring u64 [slot 513][dir 2][B 32][H/2 256].
// Slice 0 must hold stamp=0, h=0. Other slices: 0xAA poison != any stamp.

__global__ void init_ring_kernel(u64* __restrict__ ring) {
  int i = blockIdx.x * blockDim.x + threadIdx.x;  // 64*256 = 16384 = 2*SLICE_U64
  ring[i] = 0ull;  // slices (t=0, d=0/1): stamp 0, data 0
}

__global__ void convert_x_kernel(const float* __restrict__ x, _Float16* __restrict__ xh) {
  size_t i = (size_t)blockIdx.x * blockDim.x + threadIdx.x;  // 2,097,152 groups of 4
  f32x4 v = ((const f32x4*)x)[i];
  half4 h;
  h[0] = (_Float16)v[0]; h[1] = (_Float16)v[1];
  h[2] = (_Float16)v[2]; h[3] = (_Float16)v[3];
  ((half4*)xh)[i] = h;
}

__global__ __launch_bounds__(NTHR, 1)
void lstm_stamped_kernel(const _Float16* __restrict__ xh,
                         const float* __restrict__ WihF, const float* __restrict__ WhhF,
                         const float* __restrict__ bihF, const float* __restrict__ bhhF,
                         const float* __restrict__ WihB, const float* __restrict__ WhhB,
                         const float* __restrict__ bihB, const float* __restrict__ bhhB,
                         float* __restrict__ out, u64* __restrict__ ring) {
  const int blk = blockIdx.x;
  const int d = blk & 1;    // direction
  const int w = blk >> 1;   // 0..63: owns h-cols [w*8, w*8+8)
  const int tid = threadIdx.x;
  const int lane = tid & 63;
  const int wv = tid >> 6;  // wave 0..3
  const int nt = wv >> 1;   // n-tile (16 gate-cols each)
  const int kh = wv & 1;    // k-half (8 kblocks of 32)

  const float* Wih = d ? WihB : WihF;
  const float* Whh = d ? WhhB : WhhF;
  const float* bih = d ? bihB : bihF;
  const float* bhh = d ? bhhB : bhhF;

  // MFMA 16x16x32 lane roles (m89-verified): A[m=lane&15][k=quad*8+j],
  // B[k][n=lane&15], C/D col=lane&15 row=quad*4+reg.
  const int nn = lane & 15;
  const int quad = lane >> 4;
  const int n32 = nt * 16 + nn;
  const int gg = n32 >> 3;
  const int jj = n32 & 7;
  const int gc = gg * HDIM + w * 8 + jj;  // global gate-col

  // stationary fp16 weight fragments
  half8 wihf[8], whhf[8];
#pragma unroll
  for (int kbi = 0; kbi < 8; ++kbi) {
    const int k0 = (kh * 8 + kbi) * 32 + quad * 8;
    const f32x4* pi = (const f32x4*)(Wih + (size_t)gc * HDIM + k0);
    const f32x4* ph = (const f32x4*)(Whh + (size_t)gc * HDIM + k0);
    f32x4 i0 = pi[0], i1 = pi[1], h0 = ph[0], h1 = ph[1];
    half8 a, b;
#pragma unroll
    for (int j = 0; j < 4; ++j) {
      a[j] = (_Float16)i0[j]; a[4 + j] = (_Float16)i1[j];
      b[j] = (_Float16)h0[j]; b[4 + j] = (_Float16)h1[j];
    }
    wihf[kbi] = a; whhf[kbi] = b;
  }
  const float bseed = kh ? 0.f : (bih[gc] + bhh[gc]);  // kh==0 wave only

  // cell-update role
  const int cb = tid >> 3;
  const int cj = tid & 7;
  const int cmt = cb >> 4;
  const int creg = cb & 3;
  const int crow = (cb & 15) >> 2;
  float c = 0.f;

  __shared__ f32x4 part[8][64];

  const int tstep = d ? -1 : 1;
  int tx = d ? (TDIM - 1) : 0;

  // prologue: prefetch x fragments for step 0
  half8 xf0[8], xf1[8];
#pragma unroll
  for (int kbi = 0; kbi < 8; ++kbi) {
    const int k0 = (kh * 8 + kbi) * 32 + quad * 8;
    xf0[kbi] = *(const half8*)(xh + ((size_t)nn * TDIM + tx) * HDIM + k0);
    xf1[kbi] = *(const half8*)(xh + ((size_t)(16 + nn) * TDIM + tx) * HDIM + k0);
  }

  for (int s = 0; s < TDIM; ++s, tx += tstep) {
    f32x4 acc0 = {bseed, bseed, bseed, bseed};
    f32x4 acc1 = acc0;

    // ---- x MFMAs from prefetched registers (off the critical chain) ----
#pragma unroll
    for (int kbi = 0; kbi < 8; ++kbi) {
      acc0 = __builtin_amdgcn_mfma_f32_16x16x32_f16(xf0[kbi], wihf[kbi], acc0, 0, 0, 0);
      acc1 = __builtin_amdgcn_mfma_f32_16x16x32_f16(xf1[kbi], wihf[kbi], acc1, 0, 0, 0);
    }

    // ---- issue next step's x loads (overlap with poll below) ----
    int txn = tx + tstep;
    txn = txn < 0 ? 0 : (txn >= TDIM ? TDIM - 1 : txn);
    half8 xn0[8], xn1[8];
#pragma unroll
    for (int kbi = 0; kbi < 8; ++kbi) {
      const int k0 = (kh * 8 + kbi) * 32 + quad * 8;
      xn0[kbi] = *(const half8*)(xh + ((size_t)nn * TDIM + txn) * HDIM + k0);
      xn1[kbi] = *(const half8*)(xh + ((size_t)(16 + nn) * TDIM + txn) * HDIM + k0);
    }

    // ---- h phase: poll stamped words directly (flag==data, one trip) ----
    const u64* slice = ring + ((size_t)s * 2 + d) * SLICE_U64;
    const unsigned tag = (unsigned)s;
#pragma unroll
    for (int kbi = 0; kbi < 8; ++kbi) {
      const int k0 = (kh * 8 + kbi) * 32 + quad * 8;
      const u64* p0 = slice + nn * (HDIM / 2) + (k0 >> 1);
      const u64* p1 = slice + (16 + nn) * (HDIM / 2) + (k0 >> 1);
      u64 q0a, q0b, q0c, q0d, q1a, q1b, q1c, q1d;
      for (;;) {
        q0a = __hip_atomic_load(p0 + 0, __ATOMIC_RELAXED, __HIP_MEMORY_SCOPE_AGENT);
        q0b = __hip_atomic_load(p0 + 1, __ATOMIC_RELAXED, __HIP_MEMORY_SCOPE_AGENT);
        q0c = __hip_atomic_load(p0 + 2, __ATOMIC_RELAXED, __HIP_MEMORY_SCOPE_AGENT);
        q0d = __hip_atomic_load(p0 + 3, __ATOMIC_RELAXED, __HIP_MEMORY_SCOPE_AGENT);
        q1a = __hip_atomic_load(p1 + 0, __ATOMIC_RELAXED, __HIP_MEMORY_SCOPE_AGENT);
        q1b = __hip_atomic_load(p1 + 1, __ATOMIC_RELAXED, __HIP_MEMORY_SCOPE_AGENT);
        q1c = __hip_atomic_load(p1 + 2, __ATOMIC_RELAXED, __HIP_MEMORY_SCOPE_AGENT);
        q1d = __hip_atomic_load(p1 + 3, __ATOMIC_RELAXED, __HIP_MEMORY_SCOPE_AGENT);
        const bool ok = ((unsigned)(q0a >> 32) == tag) & ((unsigned)(q0b >> 32) == tag) &
                        ((unsigned)(q0c >> 32) == tag) & ((unsigned)(q0d >> 32) == tag) &
                        ((unsigned)(q1a >> 32) == tag) & ((unsigned)(q1b >> 32) == tag) &
                        ((unsigned)(q1c >> 32) == tag) & ((unsigned)(q1d >> 32) == tag);
        if (__ballot(ok) == ~0ull) break;
      }
      u32x4 lo0, lo1;
      lo0[0] = (unsigned)q0a; lo0[1] = (unsigned)q0b; lo0[2] = (unsigned)q0c; lo0[3] = (unsigned)q0d;
      lo1[0] = (unsigned)q1a; lo1[1] = (unsigned)q1b; lo1[2] = (unsigned)q1c; lo1[3] = (unsigned)q1d;
      half8 a0 = __builtin_bit_cast(half8, lo0);
      half8 a1 = __builtin_bit_cast(half8, lo1);
      acc0 = __builtin_amdgcn_mfma_f32_16x16x32_f16(a0, whhf[kbi], acc0, 0, 0, 0);
      acc1 = __builtin_amdgcn_mfma_f32_16x16x32_f16(a1, whhf[kbi], acc1, 0, 0, 0);
    }

    // ---- cross-wave reduction ----
    part[wv * 2 + 0][lane] = acc0;
    part[wv * 2 + 1][lane] = acc1;
    __syncthreads();

    float gv[4];
#pragma unroll
    for (int g4 = 0; g4 < 4; ++g4) {
      const int n32g = g4 * 8 + cj;
      const int ntg = n32g >> 4;
      const int ng = n32g & 15;
      const int lg = (crow << 4) | ng;
      f32x4 p0 = part[(ntg * 2 + 0) * 2 + cmt][lg];
      f32x4 p1 = part[(ntg * 2 + 1) * 2 + cmt][lg];
      gv[g4] = p0[creg] + p1[creg];
    }
    const float ig = sigm(gv[0]);
    const float fg = sigm(gv[1]);
    const float gt = tanh_f(gv[2]);
    const float og = sigm(gv[3]);
    c = fg * c + ig * gt;
    const float h = og * tanh_f(c);

    // ---- publish: ONE stamped u64 store per fp16 pair, fire-and-forget ----
    const float hn = __shfl_xor(h, 1);
    {
      u64* wslice = ring + ((size_t)(s + 1) * 2 + d) * SLICE_U64;
      if (!(tid & 1)) {
        const unsigned lo = (unsigned)__builtin_bit_cast(unsigned short, (_Float16)h);
        const unsigned hi = (unsigned)__builtin_bit_cast(unsigned short, (_Float16)hn);
        const u64 val = ((u64)(unsigned)(s + 1) << 32) | (u64)(lo | (hi << 16));
        __hip_atomic_store(wslice + cb * (HDIM / 2) + ((w * 8 + cj) >> 1), val,
                           __ATOMIC_RELAXED, __HIP_MEMORY_SCOPE_AGENT);
      }
    }

    // LDS reuse guard for next iteration (gathers done before next part[] write)
    __syncthreads();

    out[((size_t)cb * TDIM + tx) * (2 * HDIM) + d * HDIM + w * 8 + cj] = h;

    // rotate x prefetch
#pragma unroll
    for (int kbi = 0; kbi < 8; ++kbi) { xf0[kbi] = xn0[kbi]; xf1[kbi] = xn1[kbi]; }
  }
}

// ================= fallback (R4) path =================
__global__ void init_ws_kernel(int* __restrict__ cnt, int* __restrict__ hbuf_i) {
  int i = blockIdx.x * blockDim.x + threadIdx.x;
  if (i < 2 * SLOTS * CSTRIDE)
    __hip_atomic_store(cnt + i, 0, __ATOMIC_RELAXED, __HIP_MEMORY_SCOPE_AGENT);
  if (i < 2 * SLICE_INTS)
    __hip_atomic_store(hbuf_i + i, 0, __ATOMIC_RELAXED, __HIP_MEMORY_SCOPE_AGENT);
}

template <bool RING>
__global__ __launch_bounds__(NTHR, 1)
void lstm_kernel(const float* __restrict__ x,
                 const float* __restrict__ WihF, const float* __restrict__ WhhF,
                 const float* __restrict__ bihF, const float* __restrict__ bhhF,
                 const float* __restrict__ WihB, const float* __restrict__ WhhB,
                 const float* __restrict__ bihB, const float* __restrict__ bhhB,
                 float* __restrict__ out,
                 int* __restrict__ cnt, int* __restrict__ hbuf) {
  const int blk = blockIdx.x;
  const int d = blk & 1;
  const int w = blk >> 1;
  const int tid = threadIdx.x;
  const int lane = tid & 63;
  const int wv = tid >> 6;
  const int nt = wv >> 1;
  const int kh = wv & 1;

  const float* Wih = d ? WihB : WihF;
  const float* Whh = d ? WhhB : WhhF;
  const float* bih = d ? bihB : bihF;
  const float* bhh = d ? bhhB : bhhF;

  const int nn = lane & 15;
  const int quad = lane >> 4;
  const int n32 = nt * 16 + nn;
  const int gg = n32 >> 3;
  const int jj = n32 & 7;
  const int gc = gg * HDIM + w * 8 + jj;

  half8 wihf[8], whhf[8];
#pragma unroll
  for (int kbi = 0; kbi < 8; ++kbi) {
    const int k0 = (kh * 8 + kbi) * 32 + quad * 8;
    const f32x4* pi = (const f32x4*)(Wih + (size_t)gc * HDIM + k0);
    const f32x4* ph = (const f32x4*)(Whh + (size_t)gc * HDIM + k0);
    f32x4 i0 = pi[0], i1 = pi[1], h0 = ph[0], h1 = ph[1];
    half8 a, b;
#pragma unroll
    for (int j = 0; j < 4; ++j) {
      a[j] = (_Float16)i0[j]; a[4 + j] = (_Float16)i1[j];
      b[j] = (_Float16)h0[j]; b[4 + j] = (_Float16)h1[j];
    }
    wihf[kbi] = a; whhf[kbi] = b;
  }
  const float bseed = kh ? 0.f : (bih[gc] + bhh[gc]);

  const int cb = tid >> 3;
  const int cj = tid & 7;
  const int cmt = cb >> 4;
  const int creg = cb & 3;
  const int crow = (cb & 15) >> 2;
  float c = 0.f;

  __shared__ f32x4 part[8][64];

  const int tstep = d ? -1 : 1;
  int tx = d ? (TDIM - 1) : 0;

  for (int s = 0; s < TDIM; ++s, tx += tstep) {
    f32x4 acc0 = {bseed, bseed, bseed, bseed};
    f32x4 acc1 = acc0;

#pragma unroll
    for (int kbi = 0; kbi < 8; ++kbi) {
      const int k0 = (kh * 8 + kbi) * 32 + quad * 8;
      {
        const f32x4* px = (const f32x4*)(x + ((size_t)nn * TDIM + tx) * HDIM + k0);
        f32x4 u0 = px[0], u1 = px[1];
        half8 ax;
#pragma unroll
        for (int j = 0; j < 4; ++j) { ax[j] = (_Float16)u0[j]; ax[4 + j] = (_Float16)u1[j]; }
        acc0 = __builtin_amdgcn_mfma_f32_16x16x32_f16(ax, wihf[kbi], acc0, 0, 0, 0);
      }
      {
        const f32x4* px = (const f32x4*)(x + ((size_t)(16 + nn) * TDIM + tx) * HDIM + k0);
        f32x4 u0 = px[0], u1 = px[1];
        half8 ax;
#pragma unroll
        for (int j = 0; j < 4; ++j) { ax[j] = (_Float16)u0[j]; ax[4 + j] = (_Float16)u1[j]; }
        acc1 = __builtin_amdgcn_mfma_f32_16x16x32_f16(ax, wihf[kbi], acc1, 0, 0, 0);
      }
    }

    if (s > 0) {
      if (tid == 0) {
        const int* pc = cnt + (size_t)(d * SLOTS + s) * CSTRIDE;
        while (__hip_atomic_load(pc, __ATOMIC_RELAXED, __HIP_MEMORY_SCOPE_AGENT) < NWG) {}
      }
      __syncthreads();
    }

    if (RING) {
      const _Float16* hb = (const _Float16*)(hbuf + ((size_t)s * 2 + d) * SLICE_INTS);
#pragma unroll
      for (int kbi = 0; kbi < 8; ++kbi) {
        const int k0 = (kh * 8 + kbi) * 32 + quad * 8;
        half8 a0 = *(const half8*)(hb + nn * HDIM + k0);
        acc0 = __builtin_amdgcn_mfma_f32_16x16x32_f16(a0, whhf[kbi], acc0, 0, 0, 0);
        half8 a1 = *(const half8*)(hb + (16 + nn) * HDIM + k0);
        acc1 = __builtin_amdgcn_mfma_f32_16x16x32_f16(a1, whhf[kbi], acc1, 0, 0, 0);
      }
    } else {
      const unsigned long long* hb = (const unsigned long long*)(
          hbuf + ((size_t)(s & 1) * 2 + d) * SLICE_INTS);
#pragma unroll
      for (int kbi = 0; kbi < 8; ++kbi) {
        const int k0 = (kh * 8 + kbi) * 32 + quad * 8;
        {
          const unsigned long long* p = hb + (nn * (HDIM / 4) + (k0 >> 2));
          u64x2 q;
          q[0] = __hip_atomic_load(p, __ATOMIC_RELAXED, __HIP_MEMORY_SCOPE_AGENT);
          q[1] = __hip_atomic_load(p + 1, __ATOMIC_RELAXED, __HIP_MEMORY_SCOPE_AGENT);
          half8 a0 = __builtin_bit_cast(half8, q);
          acc0 = __builtin_amdgcn_mfma_f32_16x16x32_f16(a0, whhf[kbi], acc0, 0, 0, 0);
        }
        {
          const unsigned long long* p = hb + ((16 + nn) * (HDIM / 4) + (k0 >> 2));
          u64x2 q;
          q[0] = __hip_atomic_load(p, __ATOMIC_RELAXED, __HIP_MEMORY_SCOPE_AGENT);
          q[1] = __hip_atomic_load(p + 1, __ATOMIC_RELAXED, __HIP_MEMORY_SCOPE_AGENT);
          half8 a1 = __builtin_bit_cast(half8, q);
          acc1 = __builtin_amdgcn_mfma_f32_16x16x32_f16(a1, whhf[kbi], acc1, 0, 0, 0);
        }
      }
    }

    part[wv * 2 + 0][lane] = acc0;
    part[wv * 2 + 1][lane] = acc1;
    __syncthreads();

    float gv[4];
#pragma unroll
    for (int g4 = 0; g4 < 4; ++g4) {
      const int n32g = g4 * 8 + cj;
      const int ntg = n32g >> 4;
      const int ng = n32g & 15;
      const int lg = (crow << 4) | ng;
      f32x4 p0 = part[(ntg * 2 + 0) * 2 + cmt][lg];
      f32x4 p1 = part[(ntg * 2 + 1) * 2 + cmt][lg];
      gv[g4] = p0[creg] + p1[creg];
    }
    const float ig = sigm(gv[0]);
    const float fg = sigm(gv[1]);
    const float gt = tanh_f(gv[2]);
    const float og = sigm(gv[3]);
    c = fg * c + ig * gt;
    const float h = og * tanh_f(c);

    const float hn = __shfl_xor(h, 1);
    {
      const size_t tdst = RING ? (size_t)(s + 1) : (size_t)((s + 1) & 1);
      int* hw = hbuf + (tdst * 2 + d) * SLICE_INTS;
      if (!(tid & 1)) {
        const unsigned lo = (unsigned)__builtin_bit_cast(unsigned short, (_Float16)h);
        const unsigned hi = (unsigned)__builtin_bit_cast(unsigned short, (_Float16)hn);
        const int packed = (int)(lo | (hi << 16));
        __hip_atomic_store(hw + cb * (HDIM / 2) + ((w * 8 + cj) >> 1), packed,
                           __ATOMIC_RELAXED, __HIP_MEMORY_SCOPE_AGENT);
      }
    }

    __syncthreads();
    if (tid == 0) {
      __hip_atomic_fetch_add(cnt + (size_t)(d * SLOTS + s + 1) * CSTRIDE, 1,
                             __ATOMIC_RELAXED, __HIP_MEMORY_SCOPE_AGENT);
    }
    out[((size_t)cb * TDIM + tx) * (2 * HDIM) + d * HDIM + w * 8 + cj] = h;
  }
}

extern "C" void kernel_launch(void* const* d_in, const int* in_sizes, int n_in,
                              void* d_out, int out_size, void* d_ws, size_t ws_size,
                              hipStream_t stream) {
  const float* x    = (const float*)d_in[0];
  const float* WihF = (const float*)d_in[1];
  const float* WhhF = (const float*)d_in[2];
  const float* bihF = (const float*)d_in[3];
  const float* bhhF = (const float*)d_in[4];
  const float* WihB = (const float*)d_in[5];
  const float* WhhB = (const float*)d_in[6];
  const float* bihB = (const float*)d_in[7];
  const float* bhhB = (const float*)d_in[8];
  float* out = (float*)d_out;

  const size_t cnt_bytes = (size_t)2 * SLOTS * CSTRIDE * 4;            // 65,664
  const size_t xh_bytes = (size_t)BDIM * TDIM * HDIM * 2;              // 33,554,432
  const size_t ring_u64_bytes = (size_t)SLOTS * 2 * SLICE_U64 * 8;     // 67,239,936
  const size_t primary_bytes = cnt_bytes + xh_bytes + ring_u64_bytes;  // ~96 MB

  if (ws_size >= primary_bytes) {
    _Float16* xh = (_Float16*)((char*)d_ws + cnt_bytes);
    u64* ring = (u64*)((char*)d_ws + cnt_bytes + xh_bytes);
    hipLaunchKernelGGL(init_ring_kernel, dim3(64), dim3(NTHR), 0, stream, ring);
    hipLaunchKernelGGL(convert_x_kernel, dim3(8192), dim3(NTHR), 0, stream, x, xh);
    hipLaunchKernelGGL(lstm_stamped_kernel, dim3(2 * NWG), dim3(NTHR), 0, stream,
                       xh, WihF, WhhF, bihF, bhhF, WihB, WhhB, bihB, bhhB, out, ring);
    return;
  }

  int* cnt = (int*)d_ws;
  int* hbuf = (int*)((char*)d_ws + cnt_bytes);
  const size_t ring_bytes = cnt_bytes + (size_t)SLOTS * 2 * SLICE_INTS * 4;
  const bool ring = (ws_size >= ring_bytes);

  hipLaunchKernelGGL(init_ws_kernel, dim3(128), dim3(NTHR), 0, stream, cnt, hbuf);
  if (ring) {
    hipLaunchKernelGGL((lstm_kernel<true>), dim3(2 * NWG), dim3(NTHR), 0, stream,
                       x, WihF, WhhF, bihF, bhhF, WihB, WhhB, bihB, bhhB, out, cnt, hbuf);
  } else {
    hipLaunchKernelGGL((lstm_kernel<false>), dim3(2 * NWG), dim3(NTHR), 0, stream,
                       x, WihF, WhhF, bihF, bhhF, WihB, WhhB, bihB, bhhB, out, cnt, hbuf);
  }
}